// Round 8
// baseline (188.152 us; speedup 1.0000x reference)
//
#include <hip/hip_runtime.h>
#include <hip/hip_bf16.h>

#define B_SIZE 4096
#define D_SIZE 256
#define N_SIZE 8192
// features scaled by sqrt(10*log2 e) at norm time: MFMA dot = 10*log2(e)*raw_dot,
// so exp(10*raw) == exp2(dot) directly (saves one v_mul per matrix element).
#define FSCALE 3.798282555f
#define LN2    0.69314718056f

typedef __attribute__((ext_vector_type(8))) short short8;
typedef __attribute__((ext_vector_type(4))) short short4v;
typedef __attribute__((ext_vector_type(4))) float floatx4;

// ws layout (bytes):
//       0 : float Sarr[2*8192]        (65536)  per-row full exp-sum (incl diag) per teacher
//   65536 : float SS[4096]            (16384)  S-S quadrant row sums (shared by both teachers)
//   81920 : float lossAcc; int ticket (8)
//   82432 : int cnt[128]              (512)
//   82944 : int off[128]              (512)
//   83456 : int idxS[4096]            (16384)  row indices bucketed by class
//   99840 : float g[3][128][256]      (393216) per-class feature sums
//  524288 : bf16 featS|featT0|featT1  (3 x 2MB contiguous)

__device__ __forceinline__ void async16(void* lds, const void* g) {
    __builtin_amdgcn_global_load_lds(
        (const __attribute__((address_space(1))) unsigned int*)g,
        (__attribute__((address_space(3))) unsigned int*)lds, 16, 0, 0);
}

// Normalize all 3 feature sets (scaled by FSCALE); first blocks zero
// Sarr+SS+lossAcc+ticket; block 0 additionally does label histogram/prefix/scatter.
__global__ void norm_kernel(const float* __restrict__ hs,
                            const float* __restrict__ ht0,
                            const float* __restrict__ ht1,
                            __hip_bfloat16* __restrict__ dst,
                            float* __restrict__ zero_region,
                            const int* __restrict__ labels,
                            int* __restrict__ cnt, int* __restrict__ offv,
                            int* __restrict__ idxS) {
    int id  = blockIdx.x;
    int tid = threadIdx.x;
    int gid = id * 256 + tid;
    if (gid < 20482) zero_region[gid] = 0.0f;   // Sarr + SS + lossAcc + ticket

    const float* src = (id < 4096) ? (hs + id * D_SIZE)
                     : (id < 8192) ? (ht0 + (id - 4096) * D_SIZE)
                                   : (ht1 + (id - 8192) * D_SIZE);
    float x = src[tid];
    float ss = x * x;
#pragma unroll
    for (int off = 32; off > 0; off >>= 1) ss += __shfl_xor(ss, off);
    __shared__ float wsum[4];
    int wave = tid >> 6, lane = tid & 63;
    if (lane == 0) wsum[wave] = ss;
    __syncthreads();
    float tot = wsum[0] + wsum[1] + wsum[2] + wsum[3];
    float inv = 1.0f / fmaxf(sqrtf(tot), 1e-12f);
    dst[id * D_SIZE + tid] = __float2bfloat16(x * inv * FSCALE);

    if (id == 0) {   // fused scatter (histogram + prefix + bucket indices)
        __shared__ int h[128], o[128], ctr[128];
        if (tid < 128) { h[tid] = 0; ctr[tid] = 0; }
        __syncthreads();
        for (int i = tid; i < B_SIZE; i += 256) atomicAdd(&h[labels[i] & 127], 1);
        __syncthreads();
        if (tid == 0) {
            int s = 0;
            for (int c = 0; c < 128; ++c) { o[c] = s; s += h[c]; }
        }
        __syncthreads();
        for (int i = tid; i < B_SIZE; i += 256) {
            int lab = labels[i] & 127;
            int pos = o[lab] + atomicAdd(&ctr[lab], 1);
            idxS[pos] = i;
        }
        if (tid < 128) { cnt[tid] = h[tid]; offv[tid] = o[tid]; }
    }
}

// g_c = sum_{lab_j=c} f_j per set. 384 blocks (set*128+c) x 256 threads.
__global__ void gvec_kernel(const __hip_bfloat16* __restrict__ featBase,
                            const int* __restrict__ cnt,
                            const int* __restrict__ off,
                            const int* __restrict__ idxS,
                            float* __restrict__ gOut) {
    const int c   = blockIdx.x & 127;
    const int set = blockIdx.x >> 7;
    const int tid = threadIdx.x;
    const __hip_bfloat16* f = featBase + set * B_SIZE * D_SIZE;
    __shared__ int sIdx[256];
    const int n = cnt[c], o = off[c];
    float acc = 0.0f;
    for (int base = 0; base < n; base += 256) {
        int m = n - base; if (m > 256) m = 256;
        __syncthreads();
        if (tid < m) sIdx[tid] = idxS[o + base + tid];
        __syncthreads();
        for (int k = 0; k < m; ++k)
            acc += __bfloat162float(f[sIdx[k] * D_SIZE + tid]);
    }
    gOut[set * 32768 + c * 256 + tid] = acc;
}

// Symmetric S-only sim kernel + S-S dedup -- WAVE-PRIVATE staging, ZERO barriers.
// r7 lesson: doubling waves inside the barrier-lockstep made things worse
// (sync cost per unit work doubled). This version removes the lockstep: each
// wave stages its OWN 16-col group (8 KB) into its OWN LDS quarter (2x8KB
// dbuf, 64KB/block total) and iterates 16 groups independently. Staging
// addressing / LDS fragment layout / A-frags / MFMA maps are r2-verbatim
// (16-col subtile @ ks*1024 + lane*16); only base constants changed.
// Staging volume x4 (no cross-wave sharing) -- L2-resident, hidden by dbuf.
// Per group: vmcnt(0) drains own prefetch (issued one group earlier, ~free);
// no __syncthreads anywhere. (256,2): ~195 regs/wave fits 256 budget, no spill.
// Grid: 920 blocks. pb<528: teacher-0 triangle; pb>=528: teacher-1 (R>=16);
// R<16 blocks are S-S, computed once into shared SS[4096].
// Per wave (rows [rb,rb+64)), group cg (cols c16=col0+16cg):
//   c16+16 <= rb : symmetric (row sums + col atomics)
//   c16 < rb+64  : band, full 64x16 tile, row sums only (ordered pairs once)
//   else         : stop (ng = min(16,(rb+64-col0)/16) >= 4 always).
__global__ __launch_bounds__(256, 2)
void sim_kernel(const __hip_bfloat16* __restrict__ featS,
                const __hip_bfloat16* __restrict__ featT0,
                const __hip_bfloat16* __restrict__ featT1,
                float* __restrict__ Sarr) {
    __shared__ __align__(16) unsigned char sB[65536];   // wave w: [w*16384, +16KB)

    const int bid = blockIdx.x;
    const int pb  = (bid & 7) * 115 + (bid >> 3);   // XCD swizzle, 920 = 8*115
    const int t   = (pb >= 528) ? 1 : 0;
    const int p   = t ? (pb - 392) : pb;            // pb-528+136: teacher-1 R>=16
    const __hip_bfloat16* featT = t ? featT1 : featT0;

    int R = (int)((sqrtf((float)(8 * p + 1)) - 1.0f) * 0.5f);
    while ((R + 1) * (R + 2) / 2 <= p) ++R;
    while (R * (R + 1) / 2 > p) --R;
    const int C = p - R * (R + 1) / 2;

    const int tid  = threadIdx.x;
    const int w    = tid >> 6;       // 0..3
    const int l    = tid & 63;
    const int quad = l >> 4;
    const int lcol = l & 15;
    const int rb   = R * 256 + w * 64;   // this wave's 64 rows

    // S-S blocks (R<16, only in t=0 pass) write the shared SS buffer.
    float* tgt = (R < 16) ? (Sarr + 2 * N_SIZE) : (Sarr + t * N_SIZE);

    // uniform-per-block base pointers (256-aligned tiles never straddle S/T)
    const __hip_bfloat16* rowBase = (R < 16) ? featS + (R * 256) * D_SIZE
                                             : featT + (R * 256 - B_SIZE) * D_SIZE;
    const int col0 = C * 256;
    const __hip_bfloat16* colBase = (C < 16) ? featS + col0 * D_SIZE
                                             : featT + (col0 - B_SIZE) * D_SIZE;

    // A fragments: 4 row-tiles x 8 k-steps, register resident (128 VGPR)
    short8 af[4][8];
#pragma unroll
    for (int rt = 0; rt < 4; ++rt) {
        const __hip_bfloat16* ap = rowBase + (w * 64 + rt * 16 + lcol) * D_SIZE;
#pragma unroll
        for (int ks = 0; ks < 8; ++ks)
            af[rt][ks] = *reinterpret_cast<const short8*>(ap + ks * 32 + quad * 8);
    }

    float Sp[4][4];
#pragma unroll
    for (int rt = 0; rt < 4; ++rt)
#pragma unroll
        for (int r = 0; r < 4; ++r) Sp[rt][r] = 0.0f;

    unsigned char* myLds = &sB[w * 16384];

    // stage 16-col group cg into own dbuf half b (r2-verbatim addressing)
    auto stage = [&](int b, int cg) {
        const char* gp = (const char*)(colBase + cg * 16 * D_SIZE)
                       + lcol * 512 + quad * 16;
        unsigned char* lp = myLds + b * 8192;
#pragma unroll
        for (int ks = 0; ks < 8; ++ks)
            async16(lp + ks * 1024, gp + ks * 64);
    };

    int ng = (rb + 64 - col0) >> 4;          // >= 4 (R >= C); cap 16
    if (ng > 16) ng = 16;

    stage(0, 0);
    int buf = 0;
    for (int cg = 0; cg < ng; ++cg) {
        // drain own prefetch for group cg (issued one group earlier)
        asm volatile("s_waitcnt vmcnt(0)" ::: "memory");
        if (cg + 1 < ng) stage(buf ^ 1, cg + 1);

        const int c16 = col0 + cg * 16;
        const bool sym = (c16 + 16 <= rb);   // fully below diagonal band

        floatx4 acc[4];
#pragma unroll
        for (int rt = 0; rt < 4; ++rt) acc[rt] = floatx4{0.f, 0.f, 0.f, 0.f};

        __builtin_amdgcn_s_setprio(1);
#pragma unroll
        for (int ks = 0; ks < 8; ++ks) {
            short8 bf = *reinterpret_cast<const short8*>(
                myLds + buf * 8192 + ks * 1024 + l * 16);
#pragma unroll
            for (int rt = 0; rt < 4; ++rt)
                acc[rt] = __builtin_amdgcn_mfma_f32_16x16x32_bf16(
                    af[rt][ks], bf, acc[rt], 0, 0, 0);
        }
        __builtin_amdgcn_s_setprio(0);

        float Cp = 0.0f;
#pragma unroll
        for (int rt = 0; rt < 4; ++rt)
#pragma unroll
            for (int r = 0; r < 4; ++r) {
                float e = exp2f(acc[rt][r]);   // features pre-scaled
                Sp[rt][r] += e;
                Cp += e;
            }

        if (sym) {   // col c16+lcol gets e_ij summed over this wave's 64 rows
            Cp += __shfl_xor(Cp, 16);
            Cp += __shfl_xor(Cp, 32);
            if (quad == 0) atomicAdd(&tgt[c16 + lcol], Cp);
        }
        buf ^= 1;
    }

    // row-sum flush: reduce over the 16 col-lanes of each quad (r2 verbatim)
#pragma unroll
    for (int rt = 0; rt < 4; ++rt)
#pragma unroll
        for (int r = 0; r < 4; ++r) {
#pragma unroll
            for (int m = 1; m < 16; m <<= 1) Sp[rt][r] += __shfl_xor(Sp[rt][r], m);
        }
    if (lcol == 0) {
#pragma unroll
        for (int rt = 0; rt < 4; ++rt)
#pragma unroll
            for (int r = 0; r < 4; ++r) {
                int row = rb + rt * 16 + quad * 4 + r;
                atomicAdd(&tgt[row], Sp[rt][r]);
            }
    }
}

// Per-row stats + final loss. 512 blocks x 256; wave handles 8 rows.
__global__ void rowstat_kernel(const __hip_bfloat16* __restrict__ featS,
                               const __hip_bfloat16* __restrict__ featT0,
                               const __hip_bfloat16* __restrict__ featT1,
                               const int* __restrict__ labels,
                               const float* __restrict__ gAll,
                               const int* __restrict__ cnt,
                               const float* __restrict__ Sarr,
                               float* __restrict__ lossAcc,
                               int* __restrict__ ticket,
                               float* __restrict__ out) {
    __shared__ float wpart[4];
    const float* SS = Sarr + 2 * N_SIZE;
    const int tid = threadIdx.x;
    const int wv  = tid >> 6;
    const int l   = tid & 63;
    const int waveid = blockIdx.x * 4 + wv;   // 0..2047
    float psum = 0.0f;

    for (int it = 0; it < 8; ++it) {
        int R = waveid * 8 + it;              // 0..16383
        int t = R >> 13;
        int i = R & (N_SIZE - 1);
        const __hip_bfloat16* f = (i < B_SIZE) ? featS + i * D_SIZE
                                : (t ? featT1 : featT0) + (i - B_SIZE) * D_SIZE;
        int lab = labels[i & (B_SIZE - 1)] & 127;
        short4v fb = *reinterpret_cast<const short4v*>(f + l * 4);
        float fx[4];
#pragma unroll
        for (int k = 0; k < 4; ++k) {
            unsigned int u = ((unsigned int)(unsigned short)fb[k]) << 16;
            fx[k] = __uint_as_float(u);
        }
        const float* gS = gAll + lab * 256 + l * 4;
        const float* gT = gAll + (1 + t) * 32768 + lab * 256 + l * 4;
        float dot = 0.f, aii = 0.f;
#pragma unroll
        for (int k = 0; k < 4; ++k) {
            dot += fx[k] * (gS[k] + gT[k]);
            aii += fx[k] * fx[k];
        }
#pragma unroll
        for (int m = 1; m < 64; m <<= 1) {
            dot += __shfl_xor(dot, m);
            aii += __shfl_xor(aii, m);
        }
        if (l == 0) {
            float S = Sarr[t * N_SIZE + i];
            if (i < B_SIZE) S += SS[i];       // shared S-S quadrant contribution
            float M = 2.0f * (float)cnt[lab] - 1.0f;
            float E = exp2f(aii);             // scaled: exp2(aii') == exp(10*raw_aii)
            psum += logf(S - E) - LN2 * (dot - aii) / M;   // 10/FSCALE^2 == ln2
        }
    }
    if (l == 0) wpart[wv] = psum;
    __syncthreads();
    if (tid == 0) {
        atomicAdd(lossAcc, wpart[0] + wpart[1] + wpart[2] + wpart[3]);
        __threadfence();
        if (atomicAdd(ticket, 1) == 511) {
            float tot = atomicAdd(lossAcc, 0.0f);
            out[0] = tot / 16384.0f;
        }
    }
}

extern "C" void kernel_launch(void* const* d_in, const int* in_sizes, int n_in,
                              void* d_out, int out_size, void* d_ws, size_t ws_size,
                              hipStream_t stream) {
    const float* hs     = (const float*)d_in[0];
    const float* ht0    = (const float*)d_in[1];
    const float* ht1    = (const float*)d_in[2];
    const int*   labels = (const int*)d_in[3];

    char* ws = (char*)d_ws;
    float* Sarr    = (float*)(ws);
    float* lossAcc = (float*)(ws + 81920);
    int*   ticket  = (int*)(ws + 81924);
    int*   cnt     = (int*)(ws + 82432);
    int*   offv    = (int*)(ws + 82944);
    int*   idxS    = (int*)(ws + 83456);
    float* gAll    = (float*)(ws + 99840);
    __hip_bfloat16* featS  = (__hip_bfloat16*)(ws + 524288);
    __hip_bfloat16* featT0 = (__hip_bfloat16*)(ws + 524288 + 2097152);
    __hip_bfloat16* featT1 = (__hip_bfloat16*)(ws + 524288 + 2 * 2097152);

    norm_kernel<<<3 * 4096, 256, 0, stream>>>(hs, ht0, ht1, featS, (float*)ws,
                                              labels, cnt, offv, idxS);
    gvec_kernel<<<384, 256, 0, stream>>>(featS, cnt, offv, idxS, gAll);
    sim_kernel<<<920, 256, 0, stream>>>(featS, featT0, featT1, Sarr);
    rowstat_kernel<<<512, 256, 0, stream>>>(featS, featT0, featT1, labels, gAll, cnt,
                                            Sarr, lossAcc, ticket, (float*)d_out);
}

// Round 9
// 147.361 us; speedup vs baseline: 1.2768x; 1.2768x over previous
//
#include <hip/hip_runtime.h>
#include <hip/hip_bf16.h>

#define B_SIZE 4096
#define D_SIZE 256
#define N_SIZE 8192
// features scaled by sqrt(10*log2 e) at norm time: MFMA dot = 10*log2(e)*raw_dot,
// so exp(10*raw) == exp2(dot) directly (saves one v_mul per matrix element).
#define FSCALE 3.798282555f
#define LN2    0.69314718056f

typedef __attribute__((ext_vector_type(8))) short short8;
typedef __attribute__((ext_vector_type(4))) short short4v;
typedef __attribute__((ext_vector_type(4))) float floatx4;

// ws layout (bytes):
//       0 : float Sarr[2*8192]        (65536)  per-row full exp-sum (incl diag) per teacher
//   65536 : float SS[4096]            (16384)  S-S quadrant row sums (shared by both teachers)
//   81920 : float lossAcc; int ticket (8)
//   82432 : int cnt[128]              (512)
//   82944 : int off[128]              (512)
//   83456 : int idxS[4096]            (16384)  row indices bucketed by class
//   99840 : float g[3][128][256]      (393216) per-class feature sums
//  524288 : bf16 featS|featT0|featT1  (3 x 2MB contiguous)

__device__ __forceinline__ void async16(void* lds, const void* g) {
    __builtin_amdgcn_global_load_lds(
        (const __attribute__((address_space(1))) unsigned int*)g,
        (__attribute__((address_space(3))) unsigned int*)lds, 16, 0, 0);
}

// Normalize all 3 feature sets (scaled by FSCALE); first blocks zero
// Sarr+SS+lossAcc+ticket; block 0 additionally does label histogram/prefix/scatter.
__global__ void norm_kernel(const float* __restrict__ hs,
                            const float* __restrict__ ht0,
                            const float* __restrict__ ht1,
                            __hip_bfloat16* __restrict__ dst,
                            float* __restrict__ zero_region,
                            const int* __restrict__ labels,
                            int* __restrict__ cnt, int* __restrict__ offv,
                            int* __restrict__ idxS) {
    int id  = blockIdx.x;
    int tid = threadIdx.x;
    int gid = id * 256 + tid;
    if (gid < 20482) zero_region[gid] = 0.0f;   // Sarr + SS + lossAcc + ticket

    const float* src = (id < 4096) ? (hs + id * D_SIZE)
                     : (id < 8192) ? (ht0 + (id - 4096) * D_SIZE)
                                   : (ht1 + (id - 8192) * D_SIZE);
    float x = src[tid];
    float ss = x * x;
#pragma unroll
    for (int off = 32; off > 0; off >>= 1) ss += __shfl_xor(ss, off);
    __shared__ float wsum[4];
    int wave = tid >> 6, lane = tid & 63;
    if (lane == 0) wsum[wave] = ss;
    __syncthreads();
    float tot = wsum[0] + wsum[1] + wsum[2] + wsum[3];
    float inv = 1.0f / fmaxf(sqrtf(tot), 1e-12f);
    dst[id * D_SIZE + tid] = __float2bfloat16(x * inv * FSCALE);

    if (id == 0) {   // fused scatter (histogram + prefix + bucket indices)
        __shared__ int h[128], o[128], ctr[128];
        if (tid < 128) { h[tid] = 0; ctr[tid] = 0; }
        __syncthreads();
        for (int i = tid; i < B_SIZE; i += 256) atomicAdd(&h[labels[i] & 127], 1);
        __syncthreads();
        if (tid == 0) {
            int s = 0;
            for (int c = 0; c < 128; ++c) { o[c] = s; s += h[c]; }
        }
        __syncthreads();
        for (int i = tid; i < B_SIZE; i += 256) {
            int lab = labels[i] & 127;
            int pos = o[lab] + atomicAdd(&ctr[lab], 1);
            idxS[pos] = i;
        }
        if (tid < 128) { cnt[tid] = h[tid]; offv[tid] = o[tid]; }
    }
}

// FUSED sim + gvec dispatch (both depend only on norm; fusing removes one
// graph node and lets the 384 light gvec blocks pack into sim's 1.8-round
// scheduling tail ~free).
//   bid <  920 : sim block -- r2-EXACT structure (proven 55.6us, absmax 0):
//                256x256 tiles, 4 waves x 64 rows, dbuf 64-col staging,
//                S-S dedup into SS[], teacher-1 grid drops R<16 blocks.
//                + explicit s_waitcnt vmcnt(0) before the publishing barrier
//                (r4 lesson: global_load_lds completion is tracked only by
//                the issuing wave's vmcnt; drain is covered by a full group's
//                compute so it's ~free, and provably race-free).
//   bid >= 920 : gvec block gb=bid-920: g_c = sum_{lab_j=c} f_j
//                (set = gb>>7, class c = gb&127).
// r5/r7/r8 lessons kept: no launch_bounds tighter than (256,2) (regs ~220 at
// 64 rows/wave); no 8-wave lockstep; no wave-private staging.
__global__ __launch_bounds__(256, 2)
void simgvec_kernel(const __hip_bfloat16* __restrict__ featS,
                    const __hip_bfloat16* __restrict__ featT0,
                    const __hip_bfloat16* __restrict__ featT1,
                    float* __restrict__ Sarr,
                    const int* __restrict__ cnt,
                    const int* __restrict__ offv,
                    const int* __restrict__ idxS,
                    float* __restrict__ gAll) {
    __shared__ __align__(16) unsigned char sB[2][32768];

    const int bid = blockIdx.x;
    const int tid = threadIdx.x;

    if (bid >= 920) {              // ---------------- gvec path ----------------
        const int gb  = bid - 920;
        const int c   = gb & 127;
        const int set = gb >> 7;
        const __hip_bfloat16* f = featS + set * B_SIZE * D_SIZE;
        int* sIdx = (int*)&sB[0][0];
        const int n = cnt[c], o = offv[c];
        float acc = 0.0f;
        for (int base = 0; base < n; base += 256) {
            int m = n - base; if (m > 256) m = 256;
            __syncthreads();
            if (tid < m) sIdx[tid] = idxS[o + base + tid];
            __syncthreads();
            for (int k = 0; k < m; ++k)
                acc += __bfloat162float(f[sIdx[k] * D_SIZE + tid]);
        }
        gAll[set * 32768 + c * 256 + tid] = acc;
        return;
    }

    // ---------------- sim path (r2-exact) ----------------
    const int pb  = (bid & 7) * 115 + (bid >> 3);   // XCD swizzle, 920 = 8*115
    const int t   = (pb >= 528) ? 1 : 0;
    const int p   = t ? (pb - 392) : pb;            // pb-528+136: teacher-1 R>=16
    const __hip_bfloat16* featT = t ? featT1 : featT0;

    int R = (int)((sqrtf((float)(8 * p + 1)) - 1.0f) * 0.5f);
    while ((R + 1) * (R + 2) / 2 <= p) ++R;
    while (R * (R + 1) / 2 > p) --R;
    const int C = p - R * (R + 1) / 2;

    const int w    = tid >> 6;
    const int l    = tid & 63;
    const int quad = l >> 4;
    const int lcol = l & 15;
    const int row_base = R * 256 + w * 64;

    // S-S blocks (R<16, only in t=0 pass) write the shared SS buffer.
    float* tgt = (R < 16) ? (Sarr + 2 * N_SIZE) : (Sarr + t * N_SIZE);

    // A fragments: 4 row-tiles x 8 k-steps, register resident
    short8 af[4][8];
#pragma unroll
    for (int rt = 0; rt < 4; ++rt) {
        int arow = row_base + rt * 16 + lcol;
        const __hip_bfloat16* ap = (arow < B_SIZE) ? featS + arow * D_SIZE
                                                   : featT + (arow - B_SIZE) * D_SIZE;
#pragma unroll
        for (int ks = 0; ks < 8; ++ks)
            af[rt][ks] = *reinterpret_cast<const short8*>(ap + ks * 32 + quad * 8);
    }

    float Sp[4][4];
#pragma unroll
    for (int rt = 0; rt < 4; ++rt)
#pragma unroll
        for (int r = 0; r < 4; ++r) Sp[rt][r] = 0.0f;

    const int col0 = C * 256;

    auto stage = [&](int b, int cb) {
        int tb = cb + w * 16;
        const __hip_bfloat16* cp = (tb < B_SIZE) ? featS + tb * D_SIZE
                                                 : featT + (tb - B_SIZE) * D_SIZE;
        const char* gp = (const char*)cp + lcol * 512 + quad * 16;
        unsigned char* lp = &sB[b][w * 8192];
#pragma unroll
        for (int ks = 0; ks < 8; ++ks)
            async16(lp + ks * 1024, gp + ks * 64);
    };

    stage(0, col0);

    for (int g = 0; g < 4; ++g) {
        const int buf = g & 1;
        // own DMA landed BEFORE the publishing barrier (cross-wave visibility)
        asm volatile("s_waitcnt vmcnt(0)" ::: "memory");
        __syncthreads();                               // all waves' DMA landed
        if (g + 1 < 4) stage(buf ^ 1, col0 + (g + 1) * 64);

        const int gcol = col0 + g * 64;
        if (gcol > row_base) continue;                 // above diagonal: skip
        const bool diag = (gcol == row_base);

        float Cp[4] = {0.f, 0.f, 0.f, 0.f};           // per-col partial sums
#pragma unroll
        for (int up = 0; up < 2; ++up) {
            floatx4 acc[2][4];
#pragma unroll
            for (int j = 0; j < 2; ++j)
#pragma unroll
                for (int rt = 0; rt < 4; ++rt) acc[j][rt] = floatx4{0.f, 0.f, 0.f, 0.f};

            __builtin_amdgcn_s_setprio(1);
#pragma unroll
            for (int ks = 0; ks < 8; ++ks) {
                short8 bf[2];
#pragma unroll
                for (int j = 0; j < 2; ++j)
                    bf[j] = *reinterpret_cast<const short8*>(
                        &sB[buf][(up * 2 + j) * 8192 + ks * 1024 + l * 16]);
#pragma unroll
                for (int j = 0; j < 2; ++j)
#pragma unroll
                    for (int rt = 0; rt < 4; ++rt)
                        acc[j][rt] = __builtin_amdgcn_mfma_f32_16x16x32_bf16(
                            af[rt][ks], bf[j], acc[j][rt], 0, 0, 0);
            }
            __builtin_amdgcn_s_setprio(0);
#pragma unroll
            for (int j = 0; j < 2; ++j)
#pragma unroll
                for (int rt = 0; rt < 4; ++rt)
#pragma unroll
                    for (int r = 0; r < 4; ++r) {
                        float e = exp2f(acc[j][rt][r]);   // features pre-scaled
                        Sp[rt][r] += e;
                        Cp[up * 2 + j] += e;
                    }
        }

        if (!diag) {   // symmetric contribution: col j gets e_ij summed over rows
#pragma unroll
            for (int u = 0; u < 4; ++u) {
                Cp[u] += __shfl_xor(Cp[u], 16);
                Cp[u] += __shfl_xor(Cp[u], 32);
            }
            if (quad == 0) {
#pragma unroll
                for (int u = 0; u < 4; ++u)
                    atomicAdd(&tgt[gcol + u * 16 + lcol], Cp[u]);
            }
        }
    }

    // row-sum flush: reduce over the 16 col-lanes of each quad
#pragma unroll
    for (int rt = 0; rt < 4; ++rt)
#pragma unroll
        for (int r = 0; r < 4; ++r) {
#pragma unroll
            for (int m = 1; m < 16; m <<= 1) Sp[rt][r] += __shfl_xor(Sp[rt][r], m);
        }
    if (lcol == 0) {
#pragma unroll
        for (int rt = 0; rt < 4; ++rt)
#pragma unroll
            for (int r = 0; r < 4; ++r) {
                int row = row_base + rt * 16 + quad * 4 + r;
                atomicAdd(&tgt[row], Sp[rt][r]);
            }
    }
}

// Per-row stats + final loss. 512 blocks x 256; wave handles 8 rows.
__global__ void rowstat_kernel(const __hip_bfloat16* __restrict__ featS,
                               const __hip_bfloat16* __restrict__ featT0,
                               const __hip_bfloat16* __restrict__ featT1,
                               const int* __restrict__ labels,
                               const float* __restrict__ gAll,
                               const int* __restrict__ cnt,
                               const float* __restrict__ Sarr,
                               float* __restrict__ lossAcc,
                               int* __restrict__ ticket,
                               float* __restrict__ out) {
    __shared__ float wpart[4];
    const float* SS = Sarr + 2 * N_SIZE;
    const int tid = threadIdx.x;
    const int wv  = tid >> 6;
    const int l   = tid & 63;
    const int waveid = blockIdx.x * 4 + wv;   // 0..2047
    float psum = 0.0f;

    for (int it = 0; it < 8; ++it) {
        int R = waveid * 8 + it;              // 0..16383
        int t = R >> 13;
        int i = R & (N_SIZE - 1);
        const __hip_bfloat16* f = (i < B_SIZE) ? featS + i * D_SIZE
                                : (t ? featT1 : featT0) + (i - B_SIZE) * D_SIZE;
        int lab = labels[i & (B_SIZE - 1)] & 127;
        short4v fb = *reinterpret_cast<const short4v*>(f + l * 4);
        float fx[4];
#pragma unroll
        for (int k = 0; k < 4; ++k) {
            unsigned int u = ((unsigned int)(unsigned short)fb[k]) << 16;
            fx[k] = __uint_as_float(u);
        }
        const float* gS = gAll + lab * 256 + l * 4;
        const float* gT = gAll + (1 + t) * 32768 + lab * 256 + l * 4;
        float dot = 0.f, aii = 0.f;
#pragma unroll
        for (int k = 0; k < 4; ++k) {
            dot += fx[k] * (gS[k] + gT[k]);
            aii += fx[k] * fx[k];
        }
#pragma unroll
        for (int m = 1; m < 64; m <<= 1) {
            dot += __shfl_xor(dot, m);
            aii += __shfl_xor(aii, m);
        }
        if (l == 0) {
            float S = Sarr[t * N_SIZE + i];
            if (i < B_SIZE) S += SS[i];       // shared S-S quadrant contribution
            float M = 2.0f * (float)cnt[lab] - 1.0f;
            float E = exp2f(aii);             // scaled: exp2(aii') == exp(10*raw_aii)
            psum += logf(S - E) - LN2 * (dot - aii) / M;   // 10/FSCALE^2 == ln2
        }
    }
    if (l == 0) wpart[wv] = psum;
    __syncthreads();
    if (tid == 0) {
        atomicAdd(lossAcc, wpart[0] + wpart[1] + wpart[2] + wpart[3]);
        __threadfence();
        if (atomicAdd(ticket, 1) == 511) {
            float tot = atomicAdd(lossAcc, 0.0f);
            out[0] = tot / 16384.0f;
        }
    }
}

extern "C" void kernel_launch(void* const* d_in, const int* in_sizes, int n_in,
                              void* d_out, int out_size, void* d_ws, size_t ws_size,
                              hipStream_t stream) {
    const float* hs     = (const float*)d_in[0];
    const float* ht0    = (const float*)d_in[1];
    const float* ht1    = (const float*)d_in[2];
    const int*   labels = (const int*)d_in[3];

    char* ws = (char*)d_ws;
    float* Sarr    = (float*)(ws);
    float* lossAcc = (float*)(ws + 81920);
    int*   ticket  = (int*)(ws + 81924);
    int*   cnt     = (int*)(ws + 82432);
    int*   offv    = (int*)(ws + 82944);
    int*   idxS    = (int*)(ws + 83456);
    float* gAll    = (float*)(ws + 99840);
    __hip_bfloat16* featS  = (__hip_bfloat16*)(ws + 524288);
    __hip_bfloat16* featT0 = (__hip_bfloat16*)(ws + 524288 + 2097152);
    __hip_bfloat16* featT1 = (__hip_bfloat16*)(ws + 524288 + 2 * 2097152);

    norm_kernel<<<3 * 4096, 256, 0, stream>>>(hs, ht0, ht1, featS, (float*)ws,
                                              labels, cnt, offv, idxS);
    simgvec_kernel<<<1304, 256, 0, stream>>>(featS, featT0, featT1, Sarr,
                                             cnt, offv, idxS, gAll);
    rowstat_kernel<<<512, 256, 0, stream>>>(featS, featT0, featT1, labels, gAll, cnt,
                                            Sarr, lossAcc, ticket, (float*)d_out);
}